// Round 7
// baseline (777.558 us; speedup 1.0000x reference)
//
#include <hip/hip_runtime.h>
#include <hip/hip_bf16.h>

#define N 8192
#define C 256
#define NCLS 1000

typedef __bf16 bf16x8 __attribute__((ext_vector_type(8)));
typedef float floatx4 __attribute__((ext_vector_type(4)));

__device__ __forceinline__ unsigned short f2bf(float x) {
    union { float f; unsigned int u; } a; a.f = x;
    unsigned int u = a.u;
    unsigned int r = (u + 0x7fffu + ((u >> 16) & 1u)) >> 16;  // RNE
    return (unsigned short)r;
}

// --- 1. row L2-normalize + cast to bf16 ------------------------------------
__global__ __launch_bounds__(256) void k_norm(const float* __restrict__ f,
                                              unsigned short* __restrict__ fnb) {
    int wid = threadIdx.x >> 6, lane = threadIdx.x & 63;
    int row = blockIdx.x * 4 + wid;
    const float4* fr = (const float4*)(f + (size_t)row * C);
    float4 v = fr[lane];
    float ss = v.x * v.x + v.y * v.y + v.z * v.z + v.w * v.w;
    #pragma unroll
    for (int m = 1; m < 64; m <<= 1) ss += __shfl_xor(ss, m, 64);
    float scale = 1.0f / fmaxf(sqrtf(ss), 1e-8f);
    ushort4 o;
    o.x = f2bf(v.x * scale); o.y = f2bf(v.y * scale);
    o.z = f2bf(v.z * scale); o.w = f2bf(v.w * scale);
    ((ushort4*)(fnb + (size_t)row * C))[lane] = o;
}

// --- 2. class histogram (single block) -------------------------------------
__global__ __launch_bounds__(1024) void k_hist(const int* __restrict__ lab,
                                               int* __restrict__ cnt) {
    __shared__ int bins[NCLS];
    for (int i = threadIdx.x; i < NCLS; i += 1024) bins[i] = 0;
    __syncthreads();
    for (int i = threadIdx.x; i < N; i += 1024) atomicAdd(&bins[lab[i]], 1);
    __syncthreads();
    for (int i = threadIdx.x; i < NCLS; i += 1024) cnt[i] = bins[i];
}

// --- 2b. perfect_logit: streaming label-compare writer ---------------------
__global__ __launch_bounds__(256) void k_perfect(const int* __restrict__ lab,
                                                 float* __restrict__ perfect) {
    __shared__ __align__(16) int labs[N];   // 32 KiB
    const int t = threadIdx.x;
    #pragma unroll
    for (int p = 0; p < 8; ++p) {
        int idx = (p * 256 + t) * 4;
        *(int4*)&labs[idx] = *(const int4*)(lab + idx);
    }
    __syncthreads();
    const int row0 = blockIdx.x * 8;
    int lr[8];
    #pragma unroll
    for (int rr = 0; rr < 8; ++rr) lr[rr] = labs[row0 + rr];
    #pragma unroll
    for (int p = 0; p < 8; ++p) {
        int c = (p * 256 + t) * 4;
        int4 lv = *(const int4*)&labs[c];
        #pragma unroll
        for (int rr = 0; rr < 8; ++rr) {
            floatx4 pv;
            pv[0] = (lv.x == lr[rr]) ? 1.0f : -1.0f;
            pv[1] = (lv.y == lr[rr]) ? 1.0f : -1.0f;
            pv[2] = (lv.z == lr[rr]) ? 1.0f : -1.0f;
            pv[3] = (lv.w == lr[rr]) ? 1.0f : -1.0f;
            __builtin_nontemporal_store(pv,
                (floatx4*)(perfect + (size_t)(row0 + rr) * N + c));
        }
    }
}

// --- 3. row-stripe GEMM: 16 exclusive rows x 8192 cols per block -----------
// B fragments gathered straight from L2-resident fnb (no LDS staging, no
// K-loop barriers). Logits staged per 1024-col chunk in LDS, then streamed
// out as sequential nontemporal dwordx4. Exclusive rows -> no atomics.
#define CH 1024
#define STRIDE 1036   // f32 stride; 1036%32=16-bank shift per 4 rows -> 2-way max

__global__ __launch_bounds__(256) void k_gemm(
    const unsigned short* __restrict__ fnb, const int* __restrict__ lab,
    float* __restrict__ logits,
    float* __restrict__ Ssum, float* __restrict__ Psum) {
    __shared__ __align__(16) float stage[16 * STRIDE];   // 66.3 KB
    __shared__ float SrowW[4][16], ProwW[4][16];
    __shared__ int Lr[16];

    const int t = threadIdx.x;
    const int wid = t >> 6, lane = t & 63;
    const int quad = lane >> 4, l15 = lane & 15;
    const int row0 = blockIdx.x * 16;

    if (t < 16) Lr[t] = lab[row0 + t];

    // A fragments for the block's 16 rows: lane -> row l15, k = ks*32+quad*8
    bf16x8 a[8];
    const unsigned short* arow = fnb + (size_t)(row0 + l15) * C + quad * 8;
    #pragma unroll
    for (int ks = 0; ks < 8; ++ks) a[ks] = *(const bf16x8*)(arow + ks * 32);

    __syncthreads();
    int labr[4];
    #pragma unroll
    for (int r = 0; r < 4; ++r) labr[r] = Lr[quad * 4 + r];

    const float invT = 10.0f;
    float eS[4] = {0.f, 0.f, 0.f, 0.f};
    float pS[4] = {0.f, 0.f, 0.f, 0.f};

    for (int ch = 0; ch < 8; ++ch) {
        const int cwave = wid * 256;          // wave's 256-col slice of chunk
        #pragma unroll 4
        for (int tl = 0; tl < 16; ++tl) {     // 16 tiles of 16 cols per wave
            const int cloc = cwave + tl * 16; // col within chunk
            const int colAbs = ch * CH + cloc + l15;
            const unsigned short* brow =
                fnb + (size_t)colAbs * C + quad * 8;
            floatx4 acc = {};
            #pragma unroll
            for (int ks = 0; ks < 8; ++ks) {
                bf16x8 b = *(const bf16x8*)(brow + ks * 32);
                acc = __builtin_amdgcn_mfma_f32_16x16x32_bf16(a[ks], b, acc, 0, 0, 0);
            }
            int labc = lab[colAbs];
            #pragma unroll
            for (int r = 0; r < 4; ++r) {
                float v = acc[r] * invT;
                int rowAbs = row0 + quad * 4 + r;
                if (colAbs != rowAbs) {
                    eS[r] += __expf(v);
                    if (labc == labr[r]) pS[r] += v;
                }
                stage[(quad * 4 + r) * STRIDE + cloc + l15] = v;
            }
        }
        __syncthreads();
        // stream chunk: 16 rows x 4 KB, sequential NT dwordx4
        float* gbase = logits + (size_t)row0 * N + ch * CH;
        #pragma unroll
        for (int row = 0; row < 16; ++row) {
            floatx4 w = *(const floatx4*)&stage[row * STRIDE + t * 4];
            __builtin_nontemporal_store(w,
                (floatx4*)(gbase + (size_t)row * N + t * 4));
        }
        __syncthreads();
    }

    // per-row S/P: reduce across the 16 lanes of each quad, then across waves
    #pragma unroll
    for (int r = 0; r < 4; ++r) {
        float e = eS[r], p = pS[r];
        e += __shfl_xor(e, 1, 64); e += __shfl_xor(e, 2, 64);
        e += __shfl_xor(e, 4, 64); e += __shfl_xor(e, 8, 64);
        p += __shfl_xor(p, 1, 64); p += __shfl_xor(p, 2, 64);
        p += __shfl_xor(p, 4, 64); p += __shfl_xor(p, 8, 64);
        if (l15 == 0) {
            SrowW[wid][quad * 4 + r] = e;
            ProwW[wid][quad * 4 + r] = p;
        }
    }
    __syncthreads();
    if (t < 16) {
        Ssum[row0 + t] = SrowW[0][t] + SrowW[1][t] + SrowW[2][t] + SrowW[3][t];
        Psum[row0 + t] = ProwW[0][t] + ProwW[1][t] + ProwW[2][t] + ProwW[3][t];
    }
}

// --- 4. final loss reduction (single block) --------------------------------
__global__ __launch_bounds__(1024) void k_loss(
    const float* __restrict__ S, const float* __restrict__ P,
    const int* __restrict__ lab, const int* __restrict__ cnt,
    float* __restrict__ out) {
    float sum = 0.f;
    for (int i = threadIdx.x; i < N; i += 1024) {
        float Ki = (float)(cnt[lab[i]] - 1);
        float term = (P[i] - Ki * logf(S[i])) / (Ki + 1e-6f);
        sum += term;
    }
    #pragma unroll
    for (int m = 1; m < 64; m <<= 1) sum += __shfl_xor(sum, m, 64);
    __shared__ float wsum[16];
    int wid = threadIdx.x >> 6, lane = threadIdx.x & 63;
    if (lane == 0) wsum[wid] = sum;
    __syncthreads();
    if (threadIdx.x == 0) {
        float tot = 0.f;
        #pragma unroll
        for (int i = 0; i < 16; ++i) tot += wsum[i];
        out[0] = -tot / (float)N;
    }
}

extern "C" void kernel_launch(void* const* d_in, const int* in_sizes, int n_in,
                              void* d_out, int out_size, void* d_ws, size_t ws_size,
                              hipStream_t stream) {
    const float* f = (const float*)d_in[0];
    const int* lab = (const int*)d_in[1];
    float* out = (float*)d_out;
    float* logits = out + 1;
    float* perfect = out + 1 + (size_t)N * N;

    unsigned short* fnb = (unsigned short*)d_ws;                 // 4 MiB
    float* Ssum = (float*)((char*)d_ws + (size_t)N * C * 2);     // 32 KiB
    float* Psum = Ssum + N;                                      // 32 KiB
    int* cnt = (int*)(Psum + N);                                 // 4 KB

    k_norm<<<N / 4, 256, 0, stream>>>(f, fnb);
    k_hist<<<1, 1024, 0, stream>>>(lab, cnt);
    k_perfect<<<N / 8, 256, 0, stream>>>(lab, perfect);
    k_gemm<<<N / 16, 256, 0, stream>>>(fnb, lab, logits, Ssum, Psum);
    k_loss<<<1, 1024, 0, stream>>>(Ssum, Psum, lab, cnt, out);
}